// Round 9
// baseline (20198.563 us; speedup 1.0000x reference)
//
#include <hip/hip_runtime.h>
#include <hip/hip_bf16.h>

// LSTM seq2seq: B=256, T=256 enc + 256 dec, D_IN=512, HID=OUT=1024.
// Base = round-8 kernel (PASSED, 15.7ms): persistent 256 WGs (1/CU),
// threadfence release/acquire grid barrier (hierarchical, r8), glds staging,
// counted-vmcnt 4-buffer pipeline, warm-B pre-issue, 3-pass split-bf16 MFMA.
// ONE change vs r8: software L2-prefetch "touch" glds ops (depth 5) into a
// scratch LDS area warm the post-invalidate L2 ~1us before the real staging
// glds needs the lines -> staging latency exposure ~0. vmcnt ladder re-derived.

#define NB   256
#define TSEQ 256
#define DIN  512
#define HID  1024
#define G4   4096

typedef __attribute__((ext_vector_type(8))) __bf16 bf16x8;
typedef __attribute__((ext_vector_type(4))) float  f32x4;

static __device__ __forceinline__ unsigned short f2bf(float v) {
    unsigned u; __builtin_memcpy(&u, &v, 4);
    return (unsigned short)((u + 0x7FFFu + ((u >> 16) & 1u)) >> 16);  // RNE
}
static __device__ __forceinline__ float bf2f(unsigned short b) {
    unsigned u = ((unsigned)b) << 16; float f; __builtin_memcpy(&f, &u, 4); return f;
}
static __device__ __forceinline__ float fsig(float x) {
    return 1.f / (1.f + __expf(-x));
}
static __device__ __forceinline__ float ftanh(float x) {
    return 2.f / (1.f + __expf(-2.f * x)) - 1.f;   // safe at |x| large
}
static __device__ __forceinline__ void glds16(const void* g, void* l) {
    __builtin_amdgcn_global_load_lds(
        (const __attribute__((address_space(1))) unsigned int*)g,
        (__attribute__((address_space(3))) unsigned int*)l, 16, 0, 0);
}

// W [K][N] f32 -> T_hi/T_lo [N][K] bf16 split (transposed)
__global__ __launch_bounds__(256) void split_transpose(
        const float* __restrict__ W, unsigned short* __restrict__ T_hi,
        unsigned short* __restrict__ T_lo, int K, int N) {
    __shared__ float tile[64][65];
    const int kb = blockIdx.x * 64, nb = blockIdx.y * 64;
    const int tid = threadIdx.x;
    const int r = tid >> 2, c0 = (tid & 3) << 4;
    #pragma unroll
    for (int j = 0; j < 16; j += 4) {
        float4 v = *(const float4*)(W + (size_t)(kb + r) * N + nb + c0 + j);
        tile[r][c0 + j + 0] = v.x; tile[r][c0 + j + 1] = v.y;
        tile[r][c0 + j + 2] = v.z; tile[r][c0 + j + 3] = v.w;
    }
    __syncthreads();
    #pragma unroll
    for (int j = 0; j < 16; ++j) {
        float v = tile[c0 + j][r];
        unsigned short hi = f2bf(v);
        unsigned short lo = f2bf(v - bf2f(hi));
        size_t o = (size_t)(nb + r) * K + kb + c0 + j;
        T_hi[o] = hi; T_lo[o] = lo;
    }
}

// LDS: 4 staging buffers of 32KB ([A_hi 8K | A_lo 8K | B_hi 8K | B_lo 8K]) + sG
// + 4KB touch scratch. Tile layout per 8K region: [64 rows][64 k] bf16,
// byte = row*128 + ((2k)^((row&7)<<4)).
__global__ __launch_bounds__(256, 1) void lstm_persist(
        const float* __restrict__ x,
        const unsigned short* __restrict__ encT_hi, const unsigned short* __restrict__ encT_lo,
        const unsigned short* __restrict__ decT_hi, const unsigned short* __restrict__ decT_lo,
        const unsigned short* __restrict__ WhT_hi, const unsigned short* __restrict__ WhT_lo,
        const unsigned short* __restrict__ WcT_hi, const unsigned short* __restrict__ WcT_lo,
        const float* __restrict__ enc_b, const float* __restrict__ dec_b,
        const float* __restrict__ bhv, const float* __restrict__ bcv,
        unsigned short* h_hi0, unsigned short* h_lo0,
        unsigned short* h_hi1, unsigned short* h_lo1,
        unsigned short* ce_hi, unsigned short* ce_lo,
        float* c0, float* c1,
        unsigned short* x_hi0, unsigned short* x_lo0,
        unsigned short* x_hi1, unsigned short* x_lo1,
        unsigned* barcnt, float* __restrict__ out) {
    __shared__ __align__(16) char smem[131072];
    __shared__ float sG[64][68];
    __shared__ __align__(16) char tscr[4096];   // touch-prefetch garbage sink
    const int wg   = blockIdx.x;
    const int row0 = (wg >> 6) << 6;   // 4 m-blocks of 64 rows
    const int hc0  = (wg & 63) << 4;   // 64 n-groups of 16 h-cols; wg%8 pins XCD
    const int tid  = threadIdx.x;
    const int lane = tid & 63;
    const int wv   = tid >> 6;
    const int rA   = (wv >> 1) << 5;
    const int cB   = (wv & 1) << 5;
    const int n    = tid & 15, mq = tid >> 4;

    // ---- hierarchical grid barrier (r8-proven, fences preserved) ----
    unsigned bar_e = 0;
    auto gbar = [&]() {
        __syncthreads();                       // drains each thread's vmem/lds
        ++bar_e;
        if (tid == 0) {
            __threadfence();                   // release: wb dirty L2 -> coherent point
            __hip_atomic_fetch_add(barcnt + ((wg & 7) << 5), 1u,
                                   __ATOMIC_RELAXED, __HIP_MEMORY_SCOPE_AGENT);
            if (wg == 0) {
                const unsigned target = bar_e << 8;       // 256 * epoch
                for (;;) {
                    unsigned s = 0;
                    #pragma unroll
                    for (int i = 0; i < 8; ++i)
                        s += __hip_atomic_load(barcnt + (i << 5),
                                               __ATOMIC_RELAXED, __HIP_MEMORY_SCOPE_AGENT);
                    if (s >= target) break;
                    __builtin_amdgcn_s_sleep(1);
                }
                __hip_atomic_fetch_add(barcnt + 256, 1u,
                                       __ATOMIC_RELAXED, __HIP_MEMORY_SCOPE_AGENT);
            } else {
                while (__hip_atomic_load(barcnt + 256,
                                         __ATOMIC_RELAXED, __HIP_MEMORY_SCOPE_AGENT) < bar_e)
                    __builtin_amdgcn_s_sleep(2);
            }
            __threadfence();                   // acquire: inv L1/L2 (stale h gone)
        }
        __syncthreads();
    };

    // ---- phase descriptors (per-thread uniform scalars) ----
    const unsigned short *g_Axh = nullptr, *g_Axl = nullptr;   // x-type A (stride DIN)
    const unsigned short *g_Ahh = nullptr, *g_Ahl = nullptr;   // h-type A (stride HID)
    const unsigned short *g_Bh = nullptr, *g_Bl = nullptr;
    int g_sb = 0, g_kb0 = 0, g_nx = 0, g_colw0 = 0, g_arow0 = 0;
    int g_tc0 = 0, g_tcs = 0;                  // touch col mapping

    // 4 glds per half-stage; full stage = stageB + stageA = 8 vmem ops/thread.
    auto stageB = [&](int c, int buf) {
        char* bb = smem + buf * 32768;
        const int k0b = g_kb0 + (c << 6);
        const int kseg = (lane & 7) ^ ((lane >> 3) & 7);
        #pragma unroll
        for (int j = 0; j < 2; ++j) {
            const int colw = g_colw0 + (j << 3) + (lane >> 3);
            const size_t go = (size_t)colw * g_sb + k0b + (kseg << 3);
            const int gclb = (wv << 4) + (j << 3);
            glds16(g_Bh + go, bb + 16384 + (gclb << 7));
            glds16(g_Bl + go, bb + 24576 + (gclb << 7));
        }
    };
    auto stageA = [&](int c, int buf) {
        char* bb = smem + buf * 32768;
        const int kseg = (lane & 7) ^ ((lane >> 3) & 7);
        const unsigned short *Ah, *Al; int sa, ka;
        if (c < g_nx) { Ah = g_Axh; Al = g_Axl; sa = DIN; ka = c << 6; }
        else          { Ah = g_Ahh; Al = g_Ahl; sa = HID; ka = (c - g_nx) << 6; }
        #pragma unroll
        for (int j = 0; j < 2; ++j) {
            const int mb2 = (wv << 4) + (j << 3);
            const int m   = mb2 + (lane >> 3);
            const size_t go = (size_t)(g_arow0 + m) * sa + ka + (kseg << 3);
            glds16(Ah + go, bb + (mb2 << 7));
            glds16(Al + go, bb + 8192 + (mb2 << 7));
        }
    };

    // L2-warm touches: lane <-> one 128B line of chunk c (row-start 16B read).
    // 2 vmem ops each; ALL waves issue identically (per-wave vmcnt must match).
    auto touchA = [&](int c) {
        const unsigned short *Ah, *Al; int sa, ka;
        if (c < g_nx) { Ah = g_Axh; Al = g_Axl; sa = DIN; ka = c << 6; }
        else          { Ah = g_Ahh; Al = g_Ahl; sa = HID; ka = (c - g_nx) << 6; }
        const size_t go = (size_t)(g_arow0 + lane) * sa + ka;
        glds16(Ah + go, tscr);
        glds16(Al + go, tscr + 2048);
    };
    auto touchB = [&](int c) {
        const int k0b = g_kb0 + (c << 6);
        const size_t col = (size_t)((lane >> 4) * g_tcs + g_tc0 + (lane & 15));
        const size_t go = col * g_sb + k0b;
        glds16(g_Bh + go, tscr);
        glds16(g_Bl + go, tscr + 2048);
    };

    auto compute = [&](const char* bb, f32x4 (&acc)[2][2]) {
        const char* sah = bb;
        const char* sal = bb + 8192;
        const char* sbh = bb + 16384;
        const char* sbl = bb + 24576;
        #pragma unroll
        for (int kk = 0; kk < 2; ++kk) {
            const int kb = (kk << 6) | ((lane >> 4) << 4);
            bf16x8 ah[2], al[2], bh[2], bl[2];
            #pragma unroll
            for (int ms = 0; ms < 2; ++ms) {
                const int m  = rA + (ms << 4) + (lane & 15);
                const int ad = (m << 7) + (kb ^ ((m & 7) << 4));
                ah[ms] = *(const bf16x8*)(sah + ad);
                al[ms] = *(const bf16x8*)(sal + ad);
            }
            #pragma unroll
            for (int ns = 0; ns < 2; ++ns) {
                const int gcl = cB + (ns << 4) + (lane & 15);
                const int ad  = (gcl << 7) + (kb ^ ((gcl & 7) << 4));
                bh[ns] = *(const bf16x8*)(sbh + ad);
                bl[ns] = *(const bf16x8*)(sbl + ad);
            }
            #pragma unroll
            for (int ms = 0; ms < 2; ++ms)
                #pragma unroll
                for (int ns = 0; ns < 2; ++ns) {
                    acc[ms][ns] = __builtin_amdgcn_mfma_f32_16x16x32_bf16(ah[ms], bh[ns], acc[ms][ns], 0, 0, 0);
                    acc[ms][ns] = __builtin_amdgcn_mfma_f32_16x16x32_bf16(al[ms], bh[ns], acc[ms][ns], 0, 0, 0);
                    acc[ms][ns] = __builtin_amdgcn_mfma_f32_16x16x32_bf16(ah[ms], bl[ns], acc[ms][ns], 0, 0, 0);
                }
        }
    };

    // Counted-vmcnt pipeline (r8) + depth-5 L2 touch prefetch.
    // Issue order per iter c: [stageB+A(c+2) 8ops][touchA+B(c+5) 4ops].
    // Steady-state ops issued after stage(c): t(c+3) 4 + s(c+1) 8 + t(c+4) 4
    // + s(c+2) 8 + t(c+5) 4 = 28. Tail: drop terms as stages/touches cease.
    auto run_chunks = [&](int nch, f32x4 (&acc)[2][2], int preB) {
        if (!preB) { stageB(0, 0); stageA(0, 0); stageB(1, 1); stageA(1, 1); }
        else       { stageA(0, 0); stageA(1, 1); }
        touchA(2); touchB(2); touchA(3); touchB(3); touchA(4); touchB(4);
        for (int c = 0; c < nch; ++c) {
            if (c + 2 < nch) { stageB(c + 2, (c + 2) & 3); stageA(c + 2, (c + 2) & 3); }
            if (c + 5 < nch) { touchA(c + 5); touchB(c + 5); }
            const int rem = nch - 1 - c;
            if (rem >= 5)      asm volatile("s_waitcnt vmcnt(28)" ::: "memory");
            else if (rem == 4) asm volatile("s_waitcnt vmcnt(24)" ::: "memory");
            else if (rem == 3) asm volatile("s_waitcnt vmcnt(20)" ::: "memory");
            else if (rem == 2) asm volatile("s_waitcnt vmcnt(16)" ::: "memory");
            else if (rem == 1) asm volatile("s_waitcnt vmcnt(8)"  ::: "memory");
            else               asm volatile("s_waitcnt vmcnt(0)"  ::: "memory");
            __builtin_amdgcn_s_barrier();
            compute(smem + (c & 3) * 32768, acc);
        }
    };

    auto acc2sG = [&](f32x4 (&acc)[2][2]) {
        #pragma unroll
        for (int ms = 0; ms < 2; ++ms)
            #pragma unroll
            for (int ns = 0; ns < 2; ++ns)
                #pragma unroll
                for (int r = 0; r < 4; ++r)
                    sG[cB + (ns << 4) + (lane & 15)]
                      [rA + (ms << 4) + ((lane >> 4) << 2) + r] = acc[ms][ns][r];
    };

    // x[tn] -> bf16 hi/lo split, one step ahead (this WG's 64 rows x 8 cols)
    auto convert = [&](int tn) {
        unsigned short* xh = (tn & 1) ? x_hi1 : x_hi0;
        unsigned short* xl = (tn & 1) ? x_lo1 : x_lo0;
        const int r = tid & 63, cp = tid >> 6;
        const int row = row0 + r;
        const int col = ((wg & 63) << 3) + (cp << 1);
        const unsigned long long pv = __builtin_nontemporal_load(
            (const unsigned long long*)(x + ((size_t)row * TSEQ + tn) * DIN + col));
        const float fx = __uint_as_float((unsigned)pv);
        const float fy = __uint_as_float((unsigned)(pv >> 32));
        const unsigned short hx = f2bf(fx), lx = f2bf(fx - bf2f(hx));
        const unsigned short hy = f2bf(fy), ly = f2bf(fy - bf2f(hy));
        *(unsigned*)(xh + (size_t)row * DIN + col) = (unsigned)hx | ((unsigned)hy << 16);
        *(unsigned*)(xl + (size_t)row * DIN + col) = (unsigned)lx | ((unsigned)ly << 16);
    };

    // encoder bias (per-thread constants)
    const float be0 = enc_b[hc0 + n];
    const float be1 = enc_b[HID + hc0 + n];
    const float be2 = enc_b[2 * HID + hc0 + n];
    const float be3 = enc_b[3 * HID + hc0 + n];

    // ================= encoder: 256 steps =================
    g_Bh = encT_hi; g_Bl = encT_lo; g_sb = 1536; g_kb0 = 0; g_nx = 8;
    g_colw0 = wv * HID + hc0; g_arow0 = row0;
    g_tc0 = hc0; g_tcs = HID;
    convert(0);
    stageB(0, 0); stageB(1, 1);        // pre-issue enc t=0 B; drained by gbar
    gbar();
    for (int t = 0; t < TSEQ; ++t) {
        g_Axh = (t & 1) ? x_hi1 : x_hi0;  g_Axl = (t & 1) ? x_lo1 : x_lo0;
        g_Ahh = (t & 1) ? h_hi1 : h_hi0;  g_Ahl = (t & 1) ? h_lo1 : h_lo0;
        unsigned short* Ohh = (t & 1) ? h_hi0 : h_hi1;
        unsigned short* Ohl = (t & 1) ? h_lo0 : h_lo1;
        f32x4 acc[2][2];
        { f32x4 z; z[0]=0.f;z[1]=0.f;z[2]=0.f;z[3]=0.f;
          acc[0][0]=z;acc[0][1]=z;acc[1][0]=z;acc[1][1]=z; }
        run_chunks(24, acc, 1);
        acc2sG(acc);
        __syncthreads();
        #pragma unroll
        for (int q = 0; q < 4; ++q) {
            const int m = mq + (q << 4);
            const int grow = row0 + m;
            const float gi = sG[n][m] + be0;
            const float gf = sG[16 + n][m] + be1;
            const float go = sG[32 + n][m] + be2;
            const float gg = sG[48 + n][m] + be3;
            const float si = fsig(gi), sf = fsig(gf), so = fsig(go);
            const float tg = ftanh(gg);
            const size_t ci = (size_t)grow * HID + hc0 + n;
            const float cnew = sf * c0[ci] + si * tg;
            c0[ci] = cnew;
            const float hnew = so * ftanh(cnew);
            const unsigned short hh = f2bf(hnew);
            Ohh[ci] = hh; Ohl[ci] = f2bf(hnew - bf2f(hh));
            if (t == TSEQ - 1) {
                const unsigned short ch = f2bf(cnew);
                ce_hi[ci] = ch; ce_lo[ci] = f2bf(cnew - bf2f(ch));
            }
        }
        if (t < TSEQ - 1) {
            convert(t + 1);
            stageB(0, 0); stageB(1, 1);    // next step's weights: read-only, safe
        }
        gbar();
    }

    // ============ dec_const: h_enc @ dec_W[0:1024] + dec_b -> 16 regs ============
    float dk[16];
    {
        g_Bh = decT_hi; g_Bl = decT_lo; g_sb = 2048; g_kb0 = 0; g_nx = 0;
        g_Ahh = h_hi0; g_Ahl = h_lo0;       // h_enc (t=255 wrote buf 0)
        g_colw0 = wv * HID + hc0; g_arow0 = row0;
        g_tc0 = hc0; g_tcs = HID;
        f32x4 acc[2][2];
        { f32x4 z; z[0]=0.f;z[1]=0.f;z[2]=0.f;z[3]=0.f;
          acc[0][0]=z;acc[0][1]=z;acc[1][0]=z;acc[1][1]=z; }
        run_chunks(16, acc, 0);
        acc2sG(acc);
        __syncthreads();
        #pragma unroll
        for (int q = 0; q < 4; ++q) {
            const int m = mq + (q << 4);
            dk[q * 4 + 0] = sG[n][m]      + dec_b[hc0 + n];
            dk[q * 4 + 1] = sG[16 + n][m] + dec_b[HID + hc0 + n];
            dk[q * 4 + 2] = sG[32 + n][m] + dec_b[2 * HID + hc0 + n];
            dk[q * 4 + 3] = sG[48 + n][m] + dec_b[3 * HID + hc0 + n];
        }
        gbar();
    }

    // ============ projections: h_cur = h_enc@Wh+bh ; c_cur = c_enc@Wc+bc ============
    if (wg < 128) {
        const int isWc = wg >> 6;
        const int wgl  = wg & 63;
        const int mgp = wgl >> 4, ngp = wgl & 15;
        g_arow0 = mgp << 6;
        g_colw0 = (ngp << 6) + (wv << 4);
        g_Bh = isWc ? WcT_hi : WhT_hi;  g_Bl = isWc ? WcT_lo : WhT_lo;
        g_sb = 1024; g_kb0 = 0; g_nx = 0;
        g_Ahh = isWc ? ce_hi : h_hi0;   g_Ahl = isWc ? ce_lo : h_lo0;
        g_tc0 = ngp << 6; g_tcs = 16;
        f32x4 acc[2][2];
        { f32x4 z; z[0]=0.f;z[1]=0.f;z[2]=0.f;z[3]=0.f;
          acc[0][0]=z;acc[0][1]=z;acc[1][0]=z;acc[1][1]=z; }
        run_chunks(16, acc, 0);
        #pragma unroll
        for (int ms = 0; ms < 2; ++ms)
            #pragma unroll
            for (int ns = 0; ns < 2; ++ns)
                #pragma unroll
                for (int r = 0; r < 4; ++r) {
                    const int rowp = (mgp << 6) + rA + (ms << 4) + ((lane >> 4) << 2) + r;
                    const int colp = (ngp << 6) + cB + (ns << 4) + (lane & 15);
                    const size_t o = (size_t)rowp * HID + colp;
                    if (isWc) {
                        c1[o] = acc[ms][ns][r] + bcv[colp];
                    } else {
                        const float v = acc[ms][ns][r] + bhv[colp];
                        const unsigned short hh = f2bf(v);
                        h_hi1[o] = hh; h_lo1[o] = f2bf(v - bf2f(hh));
                    }
                }
    }
    gbar();

    // ================= decoder: 256 steps =================
    g_Bh = decT_hi; g_Bl = decT_lo; g_sb = 2048; g_kb0 = 1024; g_nx = 0;
    g_colw0 = wv * HID + hc0; g_arow0 = row0;
    g_tc0 = hc0; g_tcs = HID;
    stageB(0, 0); stageB(1, 1);           // pre-issue dec t=0 B (counted by vmcnt)
    for (int t = 0; t < TSEQ; ++t) {
        g_Ahh = (t & 1) ? h_hi0 : h_hi1;  g_Ahl = (t & 1) ? h_lo0 : h_lo1;
        unsigned short* Ohh = (t & 1) ? h_hi1 : h_hi0;
        unsigned short* Ohl = (t & 1) ? h_lo1 : h_lo0;
        f32x4 acc[2][2];
        { f32x4 z; z[0]=0.f;z[1]=0.f;z[2]=0.f;z[3]=0.f;
          acc[0][0]=z;acc[0][1]=z;acc[1][0]=z;acc[1][1]=z; }
        run_chunks(16, acc, 1);
        acc2sG(acc);
        __syncthreads();
        #pragma unroll
        for (int q = 0; q < 4; ++q) {
            const int m = mq + (q << 4);
            const int grow = row0 + m;
            const float gi = sG[n][m]      + dk[q * 4 + 0];
            const float gf = sG[16 + n][m] + dk[q * 4 + 1];
            const float go = sG[32 + n][m] + dk[q * 4 + 2];
            const float gg = sG[48 + n][m] + dk[q * 4 + 3];
            const float si = fsig(gi), sf = fsig(gf), so = fsig(go);
            const float tg = ftanh(gg);
            const size_t ci = (size_t)grow * HID + hc0 + n;
            const float cnew = sf * c1[ci] + si * tg;
            c1[ci] = cnew;
            const float hnew = so * ftanh(cnew);
            const unsigned short hh = f2bf(hnew);
            Ohh[ci] = hh; Ohl[ci] = f2bf(hnew - bf2f(hh));
            __builtin_nontemporal_store(hnew,
                out + ((size_t)grow * TSEQ + t) * HID + hc0 + n);
        }
        if (t < TSEQ - 1) {
            stageB(0, 0); stageB(1, 1);    // next step's weights across barrier
            gbar();
        }
    }
}

extern "C" void kernel_launch(void* const* d_in, const int* in_sizes, int n_in,
                              void* d_out, int out_size, void* d_ws, size_t ws_size,
                              hipStream_t stream) {
    (void)in_sizes; (void)n_in; (void)out_size;
    const float* x     = (const float*)d_in[0];
    const float* enc_W = (const float*)d_in[1];
    const float* enc_b = (const float*)d_in[2];
    const float* dec_W = (const float*)d_in[3];
    const float* dec_b = (const float*)d_in[4];
    const float* Wh    = (const float*)d_in[5];
    const float* bh    = (const float*)d_in[6];
    const float* Wc    = (const float*)d_in[7];
    const float* bc    = (const float*)d_in[8];
    float* out = (float*)d_out;

    char* w = (char*)d_ws;
    size_t off = 0;
    auto alloc = [&](size_t bytes) -> void* {
        off = (off + 255) & ~(size_t)255;
        void* p = w + off;
        off += bytes;
        return p;
    };
    unsigned short* encT_hi = (unsigned short*)alloc((size_t)G4 * 1536 * 2);
    unsigned short* encT_lo = (unsigned short*)alloc((size_t)G4 * 1536 * 2);
    unsigned short* decT_hi = (unsigned short*)alloc((size_t)G4 * 2048 * 2);
    unsigned short* decT_lo = (unsigned short*)alloc((size_t)G4 * 2048 * 2);
    unsigned short* WhT_hi  = (unsigned short*)alloc((size_t)HID * HID * 2);
    unsigned short* WhT_lo  = (unsigned short*)alloc((size_t)HID * HID * 2);
    unsigned short* WcT_hi  = (unsigned short*)alloc((size_t)HID * HID * 2);
    unsigned short* WcT_lo  = (unsigned short*)alloc((size_t)HID * HID * 2);
    unsigned short* h_hi0 = (unsigned short*)alloc((size_t)NB * HID * 2);
    unsigned short* h_lo0 = (unsigned short*)alloc((size_t)NB * HID * 2);
    unsigned short* h_hi1 = (unsigned short*)alloc((size_t)NB * HID * 2);
    unsigned short* h_lo1 = (unsigned short*)alloc((size_t)NB * HID * 2);
    unsigned short* ce_hi = (unsigned short*)alloc((size_t)NB * HID * 2);
    unsigned short* ce_lo = (unsigned short*)alloc((size_t)NB * HID * 2);
    float* c0 = (float*)alloc((size_t)NB * HID * 4);
    float* c1 = (float*)alloc((size_t)NB * HID * 4);
    unsigned short* x_hi0 = (unsigned short*)alloc((size_t)NB * DIN * 2);
    unsigned short* x_lo0 = (unsigned short*)alloc((size_t)NB * DIN * 2);
    unsigned short* x_hi1 = (unsigned short*)alloc((size_t)NB * DIN * 2);
    unsigned short* x_lo1 = (unsigned short*)alloc((size_t)NB * DIN * 2);
    unsigned* barcnt = (unsigned*)alloc(2048);
    if (off > ws_size) return;  // ~74MB required

    split_transpose<<<dim3(1536 / 64, G4 / 64), 256, 0, stream>>>(enc_W, encT_hi, encT_lo, 1536, G4);
    split_transpose<<<dim3(2048 / 64, G4 / 64), 256, 0, stream>>>(dec_W, decT_hi, decT_lo, 2048, G4);
    split_transpose<<<dim3(HID / 64, HID / 64), 256, 0, stream>>>(Wh, WhT_hi, WhT_lo, HID, HID);
    split_transpose<<<dim3(HID / 64, HID / 64), 256, 0, stream>>>(Wc, WcT_hi, WcT_lo, HID, HID);
    (void)hipMemsetAsync(h_hi0, 0, (size_t)NB * HID * 2, stream);
    (void)hipMemsetAsync(h_lo0, 0, (size_t)NB * HID * 2, stream);
    (void)hipMemsetAsync(c0,    0, (size_t)NB * HID * 4, stream);
    (void)hipMemsetAsync(barcnt, 0, 2048, stream);

    lstm_persist<<<256, 256, 0, stream>>>(
        x, encT_hi, encT_lo, decT_hi, decT_lo, WhT_hi, WhT_lo, WcT_hi, WcT_lo,
        enc_b, dec_b, bh, bc,
        h_hi0, h_lo0, h_hi1, h_lo1, ce_hi, ce_lo, c0, c1,
        x_hi0, x_lo0, x_hi1, x_lo1, barcnt, out);
}

// Round 10
// 10589.536 us; speedup vs baseline: 1.9074x; 1.9074x over previous
//
#include <hip/hip_runtime.h>
#include <hip/hip_bf16.h>

// LSTM seq2seq: B=256, T=256 enc + 256 dec, D_IN=512, HID=OUT=1024.
// Base = round-8 kernel (PASSED, 15.7ms). ONE change-class vs r8: all
// cross-WG data (h, x-splits, c_enc, proj outputs) moves via agent-scope
// (sc1/LLC-coherent) instructions -- sc1 stores + aux=SC1 global_load_lds +
// agent atomic loads -- and the grid barrier's two __threadfence() calls
// (which invalidated the whole per-XCD L2 every step, forcing a 14.6MB/step
// refetch and the staging-latency exposure) are REMOVED. Weights and
// WG-private c-state stay plain -> L2-resident across all 512 steps.
// 3-pass split-bf16 MFMA (f32-accurate) unchanged.

#define NB   256
#define TSEQ 256
#define DIN  512
#define HID  1024
#define G4   4096

typedef __attribute__((ext_vector_type(8))) __bf16 bf16x8;
typedef __attribute__((ext_vector_type(4))) float  f32x4;

static __device__ __forceinline__ unsigned short f2bf(float v) {
    unsigned u; __builtin_memcpy(&u, &v, 4);
    return (unsigned short)((u + 0x7FFFu + ((u >> 16) & 1u)) >> 16);  // RNE
}
static __device__ __forceinline__ float bf2f(unsigned short b) {
    unsigned u = ((unsigned)b) << 16; float f; __builtin_memcpy(&f, &u, 4); return f;
}
static __device__ __forceinline__ float fsig(float x) {
    return 1.f / (1.f + __expf(-x));
}
static __device__ __forceinline__ float ftanh(float x) {
    return 2.f / (1.f + __expf(-2.f * x)) - 1.f;   // safe at |x| large
}
// AUX: cpol bits. 0 = normal (L1/L2 cached). 16 = SC1 -> agent-coherent
// read (same scope the proven barrier atomics use; bypasses stale L2).
template<int AUX>
static __device__ __forceinline__ void glds16(const void* g, void* l) {
    __builtin_amdgcn_global_load_lds(
        (const __attribute__((address_space(1))) unsigned int*)g,
        (__attribute__((address_space(3))) unsigned int*)l, 16, 0, AUX);
}
// Agent-scope (LLC-commit) stores for cross-WG data. vmcnt-ack => committed
// at the coherence point (same property the barrier's fetch_add relies on).
static __device__ __forceinline__ void st16_ag(unsigned short* p, unsigned short v) {
    asm volatile("global_store_short %0, %1, off sc1"
                 :: "v"(p), "v"((unsigned)v) : "memory");
}
static __device__ __forceinline__ void st32_ag(unsigned* p, unsigned v) {
    asm volatile("global_store_dword %0, %1, off sc1"
                 :: "v"(p), "v"(v) : "memory");
}

// W [K][N] f32 -> T_hi/T_lo [N][K] bf16 split (transposed)
__global__ __launch_bounds__(256) void split_transpose(
        const float* __restrict__ W, unsigned short* __restrict__ T_hi,
        unsigned short* __restrict__ T_lo, int K, int N) {
    __shared__ float tile[64][65];
    const int kb = blockIdx.x * 64, nb = blockIdx.y * 64;
    const int tid = threadIdx.x;
    const int r = tid >> 2, c0 = (tid & 3) << 4;
    #pragma unroll
    for (int j = 0; j < 16; j += 4) {
        float4 v = *(const float4*)(W + (size_t)(kb + r) * N + nb + c0 + j);
        tile[r][c0 + j + 0] = v.x; tile[r][c0 + j + 1] = v.y;
        tile[r][c0 + j + 2] = v.z; tile[r][c0 + j + 3] = v.w;
    }
    __syncthreads();
    #pragma unroll
    for (int j = 0; j < 16; ++j) {
        float v = tile[c0 + j][r];
        unsigned short hi = f2bf(v);
        unsigned short lo = f2bf(v - bf2f(hi));
        size_t o = (size_t)(nb + r) * K + kb + c0 + j;
        T_hi[o] = hi; T_lo[o] = lo;
    }
}

// LDS: 4 staging buffers of 32KB ([A_hi 8K | A_lo 8K | B_hi 8K | B_lo 8K]) + sG.
// Tile layout per 8K region: [64 rows][64 k] bf16, byte = row*128 + ((2k)^((row&7)<<4)).
__global__ __launch_bounds__(256, 1) void lstm_persist(
        const float* __restrict__ x,
        const unsigned short* __restrict__ encT_hi, const unsigned short* __restrict__ encT_lo,
        const unsigned short* __restrict__ decT_hi, const unsigned short* __restrict__ decT_lo,
        const unsigned short* __restrict__ WhT_hi, const unsigned short* __restrict__ WhT_lo,
        const unsigned short* __restrict__ WcT_hi, const unsigned short* __restrict__ WcT_lo,
        const float* __restrict__ enc_b, const float* __restrict__ dec_b,
        const float* __restrict__ bhv, const float* __restrict__ bcv,
        unsigned short* h_hi0, unsigned short* h_lo0,
        unsigned short* h_hi1, unsigned short* h_lo1,
        unsigned short* ce_hi, unsigned short* ce_lo,
        float* c0, float* c1,
        unsigned short* x_hi0, unsigned short* x_lo0,
        unsigned short* x_hi1, unsigned short* x_lo1,
        unsigned* barcnt, float* __restrict__ out) {
    __shared__ __align__(16) char smem[131072];
    __shared__ float sG[64][68];
    const int wg   = blockIdx.x;
    const int row0 = (wg >> 6) << 6;   // 4 m-blocks of 64 rows
    const int hc0  = (wg & 63) << 4;   // 64 n-groups of 16 h-cols; wg%8 pins XCD
    const int tid  = threadIdx.x;
    const int lane = tid & 63;
    const int wv   = tid >> 6;
    const int rA   = (wv >> 1) << 5;
    const int cB   = (wv & 1) << 5;
    const int n    = tid & 15, mq = tid >> 4;

    // ---- hierarchical grid barrier, NO cache-invalidating fences ----
    // All cross-WG data moves via sc1 (LLC-coherent) instructions, so the
    // barrier only needs ordering: syncthreads' vmcnt(0) drain (sc1 stores
    // ack'd = committed at LLC) -> counter add -> flag spin (agent atomics).
    unsigned bar_e = 0;
    auto gbar = [&]() {
        __syncthreads();                       // drains vmem: sc1 stores committed
        ++bar_e;
        if (tid == 0) {
            __hip_atomic_fetch_add(barcnt + ((wg & 7) << 5), 1u,
                                   __ATOMIC_RELAXED, __HIP_MEMORY_SCOPE_AGENT);
            if (wg == 0) {
                const unsigned target = bar_e << 8;       // 256 * epoch
                for (;;) {
                    unsigned s = 0;
                    #pragma unroll
                    for (int i = 0; i < 8; ++i)
                        s += __hip_atomic_load(barcnt + (i << 5),
                                               __ATOMIC_RELAXED, __HIP_MEMORY_SCOPE_AGENT);
                    if (s >= target) break;
                    __builtin_amdgcn_s_sleep(1);
                }
                __hip_atomic_fetch_add(barcnt + 256, 1u,
                                       __ATOMIC_RELAXED, __HIP_MEMORY_SCOPE_AGENT);
            } else {
                while (__hip_atomic_load(barcnt + 256,
                                         __ATOMIC_RELAXED, __HIP_MEMORY_SCOPE_AGENT) < bar_e)
                    __builtin_amdgcn_s_sleep(2);
            }
        }
        __syncthreads();
    };

    // ---- phase descriptors (per-thread uniform scalars) ----
    const unsigned short *g_Axh = nullptr, *g_Axl = nullptr;   // x-type A (stride DIN)
    const unsigned short *g_Ahh = nullptr, *g_Ahl = nullptr;   // h-type A (stride HID)
    const unsigned short *g_Bh = nullptr, *g_Bl = nullptr;
    int g_sb = 0, g_kb0 = 0, g_nx = 0, g_colw0 = 0, g_arow0 = 0;

    // 4 glds per half-stage; full stage = stageB + stageA = 8 vmem ops/thread.
    auto stageB = [&](int c, int buf) {        // weights: plain (L2-resident)
        char* bb = smem + buf * 32768;
        const int k0b = g_kb0 + (c << 6);
        const int kseg = (lane & 7) ^ ((lane >> 3) & 7);
        #pragma unroll
        for (int j = 0; j < 2; ++j) {
            const int colw = g_colw0 + (j << 3) + (lane >> 3);
            const size_t go = (size_t)colw * g_sb + k0b + (kseg << 3);
            const int gclb = (wv << 4) + (j << 3);
            glds16<0>(g_Bh + go, bb + 16384 + (gclb << 7));
            glds16<0>(g_Bl + go, bb + 24576 + (gclb << 7));
        }
    };
    auto stageA = [&](int c, int buf) {        // activations: sc1 (cross-WG)
        char* bb = smem + buf * 32768;
        const int kseg = (lane & 7) ^ ((lane >> 3) & 7);
        const unsigned short *Ah, *Al; int sa, ka;
        if (c < g_nx) { Ah = g_Axh; Al = g_Axl; sa = DIN; ka = c << 6; }
        else          { Ah = g_Ahh; Al = g_Ahl; sa = HID; ka = (c - g_nx) << 6; }
        #pragma unroll
        for (int j = 0; j < 2; ++j) {
            const int mb2 = (wv << 4) + (j << 3);
            const int m   = mb2 + (lane >> 3);
            const size_t go = (size_t)(g_arow0 + m) * sa + ka + (kseg << 3);
            glds16<16>(Ah + go, bb + (mb2 << 7));
            glds16<16>(Al + go, bb + 8192 + (mb2 << 7));
        }
    };

    auto compute = [&](const char* bb, f32x4 (&acc)[2][2]) {
        const char* sah = bb;
        const char* sal = bb + 8192;
        const char* sbh = bb + 16384;
        const char* sbl = bb + 24576;
        #pragma unroll
        for (int kk = 0; kk < 2; ++kk) {
            const int kb = (kk << 6) | ((lane >> 4) << 4);
            bf16x8 ah[2], al[2], bh[2], bl[2];
            #pragma unroll
            for (int ms = 0; ms < 2; ++ms) {
                const int m  = rA + (ms << 4) + (lane & 15);
                const int ad = (m << 7) + (kb ^ ((m & 7) << 4));
                ah[ms] = *(const bf16x8*)(sah + ad);
                al[ms] = *(const bf16x8*)(sal + ad);
            }
            #pragma unroll
            for (int ns = 0; ns < 2; ++ns) {
                const int gcl = cB + (ns << 4) + (lane & 15);
                const int ad  = (gcl << 7) + (kb ^ ((gcl & 7) << 4));
                bh[ns] = *(const bf16x8*)(sbh + ad);
                bl[ns] = *(const bf16x8*)(sbl + ad);
            }
            #pragma unroll
            for (int ms = 0; ms < 2; ++ms)
                #pragma unroll
                for (int ns = 0; ns < 2; ++ns) {
                    acc[ms][ns] = __builtin_amdgcn_mfma_f32_16x16x32_bf16(ah[ms], bh[ns], acc[ms][ns], 0, 0, 0);
                    acc[ms][ns] = __builtin_amdgcn_mfma_f32_16x16x32_bf16(al[ms], bh[ns], acc[ms][ns], 0, 0, 0);
                    acc[ms][ns] = __builtin_amdgcn_mfma_f32_16x16x32_bf16(ah[ms], bl[ns], acc[ms][ns], 0, 0, 0);
                }
        }
    };

    // T4 counted-vmcnt pipeline (r8-proven): 2 stages (16 ops) in flight
    // across each raw s_barrier; 4 buffers.
    auto run_chunks = [&](int nch, f32x4 (&acc)[2][2], int preB) {
        if (!preB) { stageB(0, 0); stageA(0, 0); stageB(1, 1); stageA(1, 1); }
        else       { stageA(0, 0); stageA(1, 1); }
        for (int c = 0; c < nch; ++c) {
            if (c + 2 < nch) {
                stageB(c + 2, (c + 2) & 3);
                stageA(c + 2, (c + 2) & 3);
                if (preB && c == 0)
                    asm volatile("s_waitcnt vmcnt(12)" ::: "memory");
                else
                    asm volatile("s_waitcnt vmcnt(16)" ::: "memory");
            } else if (c + 1 < nch) {
                asm volatile("s_waitcnt vmcnt(8)" ::: "memory");
            } else {
                asm volatile("s_waitcnt vmcnt(0)" ::: "memory");
            }
            __builtin_amdgcn_s_barrier();
            compute(smem + (c & 3) * 32768, acc);
        }
    };

    auto acc2sG = [&](f32x4 (&acc)[2][2]) {
        #pragma unroll
        for (int ms = 0; ms < 2; ++ms)
            #pragma unroll
            for (int ns = 0; ns < 2; ++ns)
                #pragma unroll
                for (int r = 0; r < 4; ++r)
                    sG[cB + (ns << 4) + (lane & 15)]
                      [rA + (ms << 4) + ((lane >> 4) << 2) + r] = acc[ms][ns][r];
    };

    // x[tn] -> bf16 hi/lo split, one step ahead (sc1 stores: read cross-WG)
    auto convert = [&](int tn) {
        unsigned short* xh = (tn & 1) ? x_hi1 : x_hi0;
        unsigned short* xl = (tn & 1) ? x_lo1 : x_lo0;
        const int r = tid & 63, cp = tid >> 6;
        const int row = row0 + r;
        const int col = ((wg & 63) << 3) + (cp << 1);
        const unsigned long long pv = __builtin_nontemporal_load(
            (const unsigned long long*)(x + ((size_t)row * TSEQ + tn) * DIN + col));
        const float fx = __uint_as_float((unsigned)pv);
        const float fy = __uint_as_float((unsigned)(pv >> 32));
        const unsigned short hx = f2bf(fx), lx = f2bf(fx - bf2f(hx));
        const unsigned short hy = f2bf(fy), ly = f2bf(fy - bf2f(hy));
        st32_ag((unsigned*)(xh + (size_t)row * DIN + col), (unsigned)hx | ((unsigned)hy << 16));
        st32_ag((unsigned*)(xl + (size_t)row * DIN + col), (unsigned)lx | ((unsigned)ly << 16));
    };

    // encoder bias (per-thread constants)
    const float be0 = enc_b[hc0 + n];
    const float be1 = enc_b[HID + hc0 + n];
    const float be2 = enc_b[2 * HID + hc0 + n];
    const float be3 = enc_b[3 * HID + hc0 + n];

    // ================= encoder: 256 steps =================
    g_Bh = encT_hi; g_Bl = encT_lo; g_sb = 1536; g_kb0 = 0; g_nx = 8;
    g_colw0 = wv * HID + hc0; g_arow0 = row0;
    convert(0);
    stageB(0, 0); stageB(1, 1);        // pre-issue enc t=0 B; drained by gbar
    gbar();
    for (int t = 0; t < TSEQ; ++t) {
        g_Axh = (t & 1) ? x_hi1 : x_hi0;  g_Axl = (t & 1) ? x_lo1 : x_lo0;
        g_Ahh = (t & 1) ? h_hi1 : h_hi0;  g_Ahl = (t & 1) ? h_lo1 : h_lo0;
        unsigned short* Ohh = (t & 1) ? h_hi0 : h_hi1;
        unsigned short* Ohl = (t & 1) ? h_lo0 : h_lo1;
        f32x4 acc[2][2];
        { f32x4 z; z[0]=0.f;z[1]=0.f;z[2]=0.f;z[3]=0.f;
          acc[0][0]=z;acc[0][1]=z;acc[1][0]=z;acc[1][1]=z; }
        run_chunks(24, acc, 1);
        acc2sG(acc);
        __syncthreads();
        #pragma unroll
        for (int q = 0; q < 4; ++q) {
            const int m = mq + (q << 4);
            const int grow = row0 + m;
            const float gi = sG[n][m] + be0;
            const float gf = sG[16 + n][m] + be1;
            const float go = sG[32 + n][m] + be2;
            const float gg = sG[48 + n][m] + be3;
            const float si = fsig(gi), sf = fsig(gf), so = fsig(go);
            const float tg = ftanh(gg);
            const size_t ci = (size_t)grow * HID + hc0 + n;
            const float cnew = sf * c0[ci] + si * tg;   // c0: WG-private, plain
            c0[ci] = cnew;
            const float hnew = so * ftanh(cnew);
            const unsigned short hh = f2bf(hnew);
            st16_ag(Ohh + ci, hh);
            st16_ag(Ohl + ci, f2bf(hnew - bf2f(hh)));
            if (t == TSEQ - 1) {
                const unsigned short ch = f2bf(cnew);
                st16_ag(ce_hi + ci, ch);
                st16_ag(ce_lo + ci, f2bf(cnew - bf2f(ch)));
            }
        }
        if (t < TSEQ - 1) {
            convert(t + 1);
            stageB(0, 0); stageB(1, 1);    // next step's weights: read-only, safe
        }
        gbar();
    }

    // ============ dec_const: h_enc @ dec_W[0:1024] + dec_b -> 16 regs ============
    float dk[16];
    {
        g_Bh = decT_hi; g_Bl = decT_lo; g_sb = 2048; g_kb0 = 0; g_nx = 0;
        g_Ahh = h_hi0; g_Ahl = h_lo0;       // h_enc (t=255 wrote buf 0)
        g_colw0 = wv * HID + hc0; g_arow0 = row0;
        f32x4 acc[2][2];
        { f32x4 z; z[0]=0.f;z[1]=0.f;z[2]=0.f;z[3]=0.f;
          acc[0][0]=z;acc[0][1]=z;acc[1][0]=z;acc[1][1]=z; }
        run_chunks(16, acc, 0);
        acc2sG(acc);
        __syncthreads();
        #pragma unroll
        for (int q = 0; q < 4; ++q) {
            const int m = mq + (q << 4);
            dk[q * 4 + 0] = sG[n][m]      + dec_b[hc0 + n];
            dk[q * 4 + 1] = sG[16 + n][m] + dec_b[HID + hc0 + n];
            dk[q * 4 + 2] = sG[32 + n][m] + dec_b[2 * HID + hc0 + n];
            dk[q * 4 + 3] = sG[48 + n][m] + dec_b[3 * HID + hc0 + n];
        }
        gbar();
    }

    // ============ projections: h_cur = h_enc@Wh+bh ; c_cur = c_enc@Wc+bc ============
    if (wg < 128) {
        const int isWc = wg >> 6;
        const int wgl  = wg & 63;
        const int mgp = wgl >> 4, ngp = wgl & 15;
        g_arow0 = mgp << 6;
        g_colw0 = (ngp << 6) + (wv << 4);
        g_Bh = isWc ? WcT_hi : WhT_hi;  g_Bl = isWc ? WcT_lo : WhT_lo;
        g_sb = 1024; g_kb0 = 0; g_nx = 0;
        g_Ahh = isWc ? ce_hi : h_hi0;   g_Ahl = isWc ? ce_lo : h_lo0;
        f32x4 acc[2][2];
        { f32x4 z; z[0]=0.f;z[1]=0.f;z[2]=0.f;z[3]=0.f;
          acc[0][0]=z;acc[0][1]=z;acc[1][0]=z;acc[1][1]=z; }
        run_chunks(16, acc, 0);
        #pragma unroll
        for (int ms = 0; ms < 2; ++ms)
            #pragma unroll
            for (int ns = 0; ns < 2; ++ns)
                #pragma unroll
                for (int r = 0; r < 4; ++r) {
                    const int rowp = (mgp << 6) + rA + (ms << 4) + ((lane >> 4) << 2) + r;
                    const int colp = (ngp << 6) + cB + (ns << 4) + (lane & 15);
                    const size_t o = (size_t)rowp * HID + colp;
                    if (isWc) {
                        st32_ag((unsigned*)(c1 + o),
                                __float_as_uint(acc[ms][ns][r] + bcv[colp]));
                    } else {
                        const float v = acc[ms][ns][r] + bhv[colp];
                        const unsigned short hh = f2bf(v);
                        st16_ag(h_hi1 + o, hh);
                        st16_ag(h_lo1 + o, f2bf(v - bf2f(hh)));
                    }
                }
    }
    gbar();

    // ================= decoder: 256 steps =================
    g_Bh = decT_hi; g_Bl = decT_lo; g_sb = 2048; g_kb0 = 1024; g_nx = 0;
    g_colw0 = wv * HID + hc0; g_arow0 = row0;
    // c-state -> registers; init from proj output (cross-WG -> agent loads)
    float creg[4];
    #pragma unroll
    for (int q = 0; q < 4; ++q) {
        const size_t ci = (size_t)(row0 + mq + (q << 4)) * HID + hc0 + n;
        creg[q] = __uint_as_float(__hip_atomic_load((const unsigned*)(c1 + ci),
                      __ATOMIC_RELAXED, __HIP_MEMORY_SCOPE_AGENT));
    }
    stageB(0, 0); stageB(1, 1);           // pre-issue dec t=0 B (counted by vmcnt)
    for (int t = 0; t < TSEQ; ++t) {
        g_Ahh = (t & 1) ? h_hi0 : h_hi1;  g_Ahl = (t & 1) ? h_lo0 : h_lo1;
        unsigned short* Ohh = (t & 1) ? h_hi1 : h_hi0;
        unsigned short* Ohl = (t & 1) ? h_lo1 : h_lo0;
        f32x4 acc[2][2];
        { f32x4 z; z[0]=0.f;z[1]=0.f;z[2]=0.f;z[3]=0.f;
          acc[0][0]=z;acc[0][1]=z;acc[1][0]=z;acc[1][1]=z; }
        run_chunks(16, acc, 1);
        acc2sG(acc);
        __syncthreads();
        #pragma unroll
        for (int q = 0; q < 4; ++q) {
            const int m = mq + (q << 4);
            const int grow = row0 + m;
            const float gi = sG[n][m]      + dk[q * 4 + 0];
            const float gf = sG[16 + n][m] + dk[q * 4 + 1];
            const float go = sG[32 + n][m] + dk[q * 4 + 2];
            const float gg = sG[48 + n][m] + dk[q * 4 + 3];
            const float si = fsig(gi), sf = fsig(gf), so = fsig(go);
            const float tg = ftanh(gg);
            const float cnew = sf * creg[q] + si * tg;
            creg[q] = cnew;
            const float hnew = so * ftanh(cnew);
            const size_t ci = (size_t)grow * HID + hc0 + n;
            const unsigned short hh = f2bf(hnew);
            st16_ag(Ohh + ci, hh);
            st16_ag(Ohl + ci, f2bf(hnew - bf2f(hh)));
            __builtin_nontemporal_store(hnew,
                out + ((size_t)grow * TSEQ + t) * HID + hc0 + n);
        }
        if (t < TSEQ - 1) {
            stageB(0, 0); stageB(1, 1);    // next step's weights across barrier
            gbar();
        }
    }
}

extern "C" void kernel_launch(void* const* d_in, const int* in_sizes, int n_in,
                              void* d_out, int out_size, void* d_ws, size_t ws_size,
                              hipStream_t stream) {
    (void)in_sizes; (void)n_in; (void)out_size;
    const float* x     = (const float*)d_in[0];
    const float* enc_W = (const float*)d_in[1];
    const float* enc_b = (const float*)d_in[2];
    const float* dec_W = (const float*)d_in[3];
    const float* dec_b = (const float*)d_in[4];
    const float* Wh    = (const float*)d_in[5];
    const float* bh    = (const float*)d_in[6];
    const float* Wc    = (const float*)d_in[7];
    const float* bc    = (const float*)d_in[8];
    float* out = (float*)d_out;

    char* w = (char*)d_ws;
    size_t off = 0;
    auto alloc = [&](size_t bytes) -> void* {
        off = (off + 255) & ~(size_t)255;
        void* p = w + off;
        off += bytes;
        return p;
    };
    unsigned short* encT_hi = (unsigned short*)alloc((size_t)G4 * 1536 * 2);
    unsigned short* encT_lo = (unsigned short*)alloc((size_t)G4 * 1536 * 2);
    unsigned short* decT_hi = (unsigned short*)alloc((size_t)G4 * 2048 * 2);
    unsigned short* decT_lo = (unsigned short*)alloc((size_t)G4 * 2048 * 2);
    unsigned short* WhT_hi  = (unsigned short*)alloc((size_t)HID * HID * 2);
    unsigned short* WhT_lo  = (unsigned short*)alloc((size_t)HID * HID * 2);
    unsigned short* WcT_hi  = (unsigned short*)alloc((size_t)HID * HID * 2);
    unsigned short* WcT_lo  = (unsigned short*)alloc((size_t)HID * HID * 2);
    unsigned short* h_hi0 = (unsigned short*)alloc((size_t)NB * HID * 2);
    unsigned short* h_lo0 = (unsigned short*)alloc((size_t)NB * HID * 2);
    unsigned short* h_hi1 = (unsigned short*)alloc((size_t)NB * HID * 2);
    unsigned short* h_lo1 = (unsigned short*)alloc((size_t)NB * HID * 2);
    unsigned short* ce_hi = (unsigned short*)alloc((size_t)NB * HID * 2);
    unsigned short* ce_lo = (unsigned short*)alloc((size_t)NB * HID * 2);
    float* c0 = (float*)alloc((size_t)NB * HID * 4);
    float* c1 = (float*)alloc((size_t)NB * HID * 4);
    unsigned short* x_hi0 = (unsigned short*)alloc((size_t)NB * DIN * 2);
    unsigned short* x_lo0 = (unsigned short*)alloc((size_t)NB * DIN * 2);
    unsigned short* x_hi1 = (unsigned short*)alloc((size_t)NB * DIN * 2);
    unsigned short* x_lo1 = (unsigned short*)alloc((size_t)NB * DIN * 2);
    unsigned* barcnt = (unsigned*)alloc(2048);
    if (off > ws_size) return;  // ~74MB required

    split_transpose<<<dim3(1536 / 64, G4 / 64), 256, 0, stream>>>(enc_W, encT_hi, encT_lo, 1536, G4);
    split_transpose<<<dim3(2048 / 64, G4 / 64), 256, 0, stream>>>(dec_W, decT_hi, decT_lo, 2048, G4);
    split_transpose<<<dim3(HID / 64, HID / 64), 256, 0, stream>>>(Wh, WhT_hi, WhT_lo, HID, HID);
    split_transpose<<<dim3(HID / 64, HID / 64), 256, 0, stream>>>(Wc, WcT_hi, WcT_lo, HID, HID);
    (void)hipMemsetAsync(h_hi0, 0, (size_t)NB * HID * 2, stream);
    (void)hipMemsetAsync(h_lo0, 0, (size_t)NB * HID * 2, stream);
    (void)hipMemsetAsync(c0,    0, (size_t)NB * HID * 4, stream);
    (void)hipMemsetAsync(barcnt, 0, 2048, stream);

    lstm_persist<<<256, 256, 0, stream>>>(
        x, encT_hi, encT_lo, decT_hi, decT_lo, WhT_hi, WhT_lo, WcT_hi, WcT_lo,
        enc_b, dec_b, bh, bc,
        h_hi0, h_lo0, h_hi1, h_lo1, ce_hi, ce_lo, c0, c1,
        x_hi0, x_lo0, x_hi1, x_lo1, barcnt, out);
}